// Round 9
// baseline (6522.770 us; speedup 1.0000x reference)
//
#include <hip/hip_runtime.h>

typedef unsigned short u16;
typedef unsigned long long u64;
typedef __bf16 bfx8 __attribute__((ext_vector_type(8)));
typedef float  fx4  __attribute__((ext_vector_type(4)));

// ---------- helpers ----------
static __device__ __forceinline__ float b2f(u16 u){
  unsigned v = ((unsigned)u) << 16;
  return __builtin_bit_cast(float, v);
}
static __device__ __forceinline__ u16 f2b(float f){
  unsigned u = __builtin_bit_cast(unsigned, f);
  u = (u + 0x7FFFu + ((u >> 16) & 1u)) >> 16;
  return (u16)u;
}
static __device__ __forceinline__ float blo(unsigned v){ return b2f((u16)(v & 0xFFFFu)); }
static __device__ __forceinline__ float bhi(unsigned v){ return b2f((u16)(v >> 16)); }
static __device__ __forceinline__ float sigm(float x){
  float cx = fminf(fmaxf(x, -30.f), 30.f);
  float e = __expf(-cx);
  return __builtin_amdgcn_rcpf(1.f + e);
}
static __device__ __forceinline__ float tanh_f(float x){
  float cx = fminf(fmaxf(x, -15.f), 15.f);
  float e = __expf(2.f * cx);
  return (e - 1.f) * __builtin_amdgcn_rcpf(e + 1.f);
}
// relaxed agent-scope 8B atomics (coherent at L3, no fences)
static __device__ __forceinline__ u64 ald64(const u64* p){
  return __hip_atomic_load(p, __ATOMIC_RELAXED, __HIP_MEMORY_SCOPE_AGENT);
}
static __device__ __forceinline__ void ast64(u64* p, u64 v){
  __hip_atomic_store(p, v, __ATOMIC_RELAXED, __HIP_MEMORY_SCOPE_AGENT);
}

// ---------- K1: embeddings + LayerNorm -> X (bf16, [T*32+b][768]) ----------
__global__ __launch_bounds__(256) void embed_ln(
    const int* __restrict__ ids, const float* __restrict__ we,
    const float* __restrict__ pe, const float* __restrict__ te,
    const float* __restrict__ lng, const float* __restrict__ lnb,
    u16* __restrict__ X)
{
  int row = blockIdx.x;            // row = t*32 + b
  int t = row >> 5, b = row & 31;
  int id = ids[b * 256 + t];
  int tid = threadIdx.x;
  int wv = tid >> 6, lane = tid & 63;
  __shared__ float red[8];
  float v[3]; float s = 0.f, s2 = 0.f;
  const float* wrow = we + (long)id * 768;
  const float* prow = pe + (long)t * 768;
#pragma unroll
  for (int u = 0; u < 3; ++u){
    int k = tid + 256 * u;
    float x = wrow[k] + prow[k] + te[k];
    v[u] = x; s += x; s2 += x * x;
  }
#pragma unroll
  for (int o = 32; o > 0; o >>= 1){ s += __shfl_xor(s, o); s2 += __shfl_xor(s2, o); }
  if (lane == 0){ red[wv] = s; red[4 + wv] = s2; }
  __syncthreads();
  float S  = red[0] + red[1] + red[2] + red[3];
  float S2 = red[4] + red[5] + red[6] + red[7];
  float mu = S * (1.f / 768.f);
  float var = S2 * (1.f / 768.f) - mu * mu;
  float rs = rsqrtf(var + 1e-12f);
#pragma unroll
  for (int u = 0; u < 3; ++u){
    int k = tid + 256 * u;
    float y = (v[u] - mu) * rs * lng[k] + lnb[k];
    X[(long)row * 768 + k] = f2b(y);
  }
}

// ---------- K2: pre-projection GEMM  PRE[d][t][b][1536] = (A @ Wih^T + bias) ----------
__global__ __launch_bounds__(256) void gemm_pre(
    const u16* __restrict__ A,      // [8192][768] bf16, row = t*32+b
    const float* __restrict__ W,    // [3072][768] f32 (both dirs)
    const float* __restrict__ bi,
    const float* __restrict__ bh,
    u16* __restrict__ pre)          // [2][256][32][1536] bf16
{
  __shared__ u16 la[64][40];
  __shared__ u16 lb[64][40];
  int m0 = blockIdx.x * 64, n0 = blockIdx.y * 64;
  int tid = threadIdx.x;
  int wv = tid >> 6, lane = tid & 63;
  int l15 = lane & 15, l4 = lane >> 4;
  int r = tid >> 2, seg = (tid & 3) * 8;
  fx4 acc[4];
#pragma unroll
  for (int i = 0; i < 4; ++i){ acc[i][0]=0.f; acc[i][1]=0.f; acc[i][2]=0.f; acc[i][3]=0.f; }
  for (int k0 = 0; k0 < 768; k0 += 32){
    __syncthreads();
    *reinterpret_cast<uint4*>(&la[r][seg]) =
        *reinterpret_cast<const uint4*>(&A[(long)(m0 + r) * 768 + k0 + seg]);
    {
      const float* src = &W[(long)(n0 + r) * 768 + k0 + seg];
      union { u16 h[8]; uint4 v; } tb;
#pragma unroll
      for (int e = 0; e < 8; ++e) tb.h[e] = f2b(src[e]);
      *reinterpret_cast<uint4*>(&lb[r][seg]) = tb.v;
    }
    __syncthreads();
    bfx8 af = __builtin_bit_cast(bfx8, *reinterpret_cast<const uint4*>(&la[wv * 16 + l15][8 * l4]));
#pragma unroll
    for (int nt = 0; nt < 4; ++nt){
      bfx8 bf = __builtin_bit_cast(bfx8, *reinterpret_cast<const uint4*>(&lb[nt * 16 + l15][8 * l4]));
      acc[nt] = __builtin_amdgcn_mfma_f32_16x16x32_bf16(af, bf, acc[nt], 0, 0, 0);
    }
  }
#pragma unroll
  for (int nt = 0; nt < 4; ++nt){
    int n = n0 + nt * 16 + l15;
    int d = (n >= 1536) ? 1 : 0;
    int np = n - d * 1536;
    float bias = bi[n] + bh[n];
#pragma unroll
    for (int q = 0; q < 4; ++q){
      int m = m0 + wv * 16 + 4 * l4 + q;
      int tt = m >> 5, bb = m & 31;
      float vv = acc[nt][q] + bias;
      pre[((long)((d * 256 + tt) * 32 + bb)) * 1536 + np] = f2b(vv);
    }
  }
}

// ---------- one LSTM sub-step for direction D (R6-proven tag-poll protocol) ----------
template<int D>
static __device__ __forceinline__ void substep(
    int s, int tid, int sl, int js, int wv, int l15, int l4, int b0, int q, int jl0,
    const u16* __restrict__ pre, u16* __restrict__ Y, u64* __restrict__ H64,
    u16 (*lwD)[386], u16 (*hb)[386], float (*gl2)[16][33],
    float& c0, float& c1, uint4& pc, uint4& pn)
{
  int tt = D ? (255 - s) : s;
  int pr = (s + 1) & 1;            // read parity (holds h_{s-1}, tag s)
  int pw = s & 1;                  // write parity (h_s, tag s+1)

  // ---- stage h_{s-1}: batch-parallel tag-poll, commit every pass (R4/R6) ----
  {
    const u64* hsrc = H64 + (long)(pr * 2 + D) * 192 * 32;
    unsigned tagv = (unsigned)s;
    for (;;){
      u64 vb[24];
#pragma unroll
      for (int i = 0; i < 24; ++i) vb[i] = ald64(&hsrc[tid + 256 * i]);
      bool ok = true;
#pragma unroll
      for (int i = 0; i < 24; ++i) ok = ok && ((unsigned)(vb[i] >> 32) == tagv);
#pragma unroll
      for (int i = 0; i < 24; ++i){
        int f = tid + 256 * i;
        int bb = f & 31, j2 = f >> 5;
        *reinterpret_cast<unsigned*>(&hb[bb][(2 * j2) ^ (8 * (bb & 7))]) = (unsigned)vb[i];
      }
      if (__syncthreads_and((int)ok)) break;
    }
  }

  // prefetch pre for s+2 AFTER poll (never inside a poll vmcnt window)
  int s2 = (s + 2 < 256) ? (s + 2) : 255;
  int t2 = D ? (255 - s2) : s2;
  const u16* pb2 = pre + ((long)(D * 256 + t2) * 32 + b0) * 1536 + js + jl0;
  uint4 p2;
  p2.x = *reinterpret_cast<const unsigned*>(pb2 + 0 * 384);
  p2.y = *reinterpret_cast<const unsigned*>(pb2 + 1 * 384);
  p2.z = *reinterpret_cast<const unsigned*>(pb2 + 2 * 384);
  p2.w = *reinterpret_cast<const unsigned*>(pb2 + 3 * 384);

  // ---- MFMA: gates(g=wv, b, jl=l15) over K=384, two interleaved chains ----
  fx4 a0a, a0b, a1a, a1b;
#pragma unroll
  for (int z = 0; z < 4; ++z){ a0a[z]=0.f; a0b[z]=0.f; a1a[z]=0.f; a1b[z]=0.f; }
#pragma unroll
  for (int kk = 0; kk < 12; kk += 2){
    int col0 = (kk * 32 + 8 * l4) ^ (8 * (l15 & 7));
    int col1 = ((kk + 1) * 32 + 8 * l4) ^ (8 * (l15 & 7));
    bfx8 bw0 = __builtin_bit_cast(bfx8, *reinterpret_cast<const uint4*>(&lwD[wv * 16 + l15][col0]));
    bfx8 h00 = __builtin_bit_cast(bfx8, *reinterpret_cast<const uint4*>(&hb[l15][col0]));
    bfx8 h10 = __builtin_bit_cast(bfx8, *reinterpret_cast<const uint4*>(&hb[16 + l15][col0]));
    bfx8 bw1 = __builtin_bit_cast(bfx8, *reinterpret_cast<const uint4*>(&lwD[wv * 16 + l15][col1]));
    bfx8 h01 = __builtin_bit_cast(bfx8, *reinterpret_cast<const uint4*>(&hb[l15][col1]));
    bfx8 h11 = __builtin_bit_cast(bfx8, *reinterpret_cast<const uint4*>(&hb[16 + l15][col1]));
    a0a = __builtin_amdgcn_mfma_f32_16x16x32_bf16(h00, bw0, a0a, 0, 0, 0);
    a1a = __builtin_amdgcn_mfma_f32_16x16x32_bf16(h10, bw0, a1a, 0, 0, 0);
    a0b = __builtin_amdgcn_mfma_f32_16x16x32_bf16(h01, bw1, a0b, 0, 0, 0);
    a1b = __builtin_amdgcn_mfma_f32_16x16x32_bf16(h11, bw1, a1b, 0, 0, 0);
  }
#pragma unroll
  for (int qq = 0; qq < 4; ++qq){
    int bb0 = (4 * l4 + qq) ^ (4 * (l15 & 7));
    int bb1 = (16 + 4 * l4 + qq) ^ (4 * (l15 & 7));
    gl2[wv][l15][bb0] = a0a[qq] + a0b[qq];
    gl2[wv][l15][bb1] = a1a[qq] + a1b[qq];
  }
  __syncthreads();

  // ---- gates + cell update (2 adjacent hidden dims per thread) ----
  int jl1 = jl0 + 1;
  int x0 = b0 ^ (4 * (jl0 & 7));
  int x1 = b0 ^ (4 * (jl1 & 7));
  float gi0 = gl2[0][jl0][x0] + blo(pc.x), gi1 = gl2[0][jl1][x1] + bhi(pc.x);
  float gf0 = gl2[1][jl0][x0] + blo(pc.y), gf1 = gl2[1][jl1][x1] + bhi(pc.y);
  float gg0 = gl2[2][jl0][x0] + blo(pc.z), gg1 = gl2[2][jl1][x1] + bhi(pc.z);
  float go0 = gl2[3][jl0][x0] + blo(pc.w), go1 = gl2[3][jl1][x1] + bhi(pc.w);
  c0 = sigm(gf0) * c0 + sigm(gi0) * tanh_f(gg0);
  float h0 = sigm(go0) * tanh_f(c0);
  c1 = sigm(gf1) * c1 + sigm(gi1) * tanh_f(gg1);
  float h1 = sigm(go1) * tanh_f(c1);

  unsigned hv = (unsigned)f2b(h0) | ((unsigned)f2b(h1) << 16);
  // fire-and-forget publish: {tag s+1, h pair}
  ast64(&H64[((long)(pw * 2 + D) * 192 + sl * 8 + q) * 32 + b0],
        ((u64)(unsigned)(s + 1) << 32) | (u64)hv);
  // layer output (plain u32 store)
  *reinterpret_cast<unsigned*>(&Y[((long)tt * 32 + b0) * 768 + D * 384 + js + jl0]) = hv;
  pc = pn; pn = p2;
}

// ---------- K3: one bidirectional LSTM layer, 24 WGs, dual-chain interleave ----------
// WG sl handles hidden slice js=sl*16 for BOTH directions, alternating
// sub-steps so each chain's L3 latency hides under the other's compute.
__global__ __launch_bounds__(256) void lstm_layer(
    const float* __restrict__ Whh,  // [2][1536][384] f32 this layer
    const u16*  __restrict__ pre,   // [2][256][32][1536] bf16
    u16* __restrict__ Y,            // [256][32][768] bf16
    u64* __restrict__ H64)          // [2 par][2 dir][192][32] tagged pairs
{
  __shared__ u16 lw[2][64][386];     // W slices (both dirs), XOR-swizzled
  __shared__ u16 hb[32][386];        // staged h, XOR-swizzled
  __shared__ float gl2[4][16][33];   // [gate][jl][b^swz]
  int sl = blockIdx.x;               // 0..23
  int js = sl * 16;
  int tid = threadIdx.x;
  int wv = tid >> 6, lane = tid & 63;
  int l15 = lane & 15, l4 = lane >> 4;
  int b0 = tid & 31, q = tid >> 5;   // q 0..7
  int jl0 = 2 * q;

  // publish h_{-1} (parity 1, tag 0, zeros) for BOTH dirs
  ast64(&H64[((long)(1 * 2 + 0) * 192 + sl * 8 + q) * 32 + b0], 0ull);
  ast64(&H64[((long)(1 * 2 + 1) * 192 + sl * 8 + q) * 32 + b0], 0ull);

  // stage Whh slices for both dirs -> lw (f32 -> bf16, swizzled)
  for (int i = tid; i < 2 * 64 * 96; i += 256){
    int dd = i / (64 * 96);
    int rem = i - dd * 64 * 96;
    int rr = rem / 96, c4 = rem - rr * 96;
    const float* src = Whh + ((long)(dd * 1536 + (rr >> 4) * 384 + js + (rr & 15))) * 384 + 4 * c4;
    float4 v = *reinterpret_cast<const float4*>(src);
    short4 pk;
    pk.x = (short)f2b(v.x); pk.y = (short)f2b(v.y);
    pk.z = (short)f2b(v.z); pk.w = (short)f2b(v.w);
    *reinterpret_cast<short4*>(&lw[dd][rr][(4 * c4) ^ (8 * (rr & 7))]) = pk;
  }
  __syncthreads();

  float c00 = 0.f, c01 = 0.f;   // dir 0 cell states (pair0, pair1)
  float c10 = 0.f, c11 = 0.f;   // dir 1 cell states

  // prefetch pre for s=0,1 for both dirs (distance-2 pipeline)
  uint4 pc0, pn0, pc1, pn1;
  {
    const u16* p00 = pre + ((long)(0 * 256 + 0)   * 32 + b0) * 1536 + js + jl0;
    const u16* p01 = pre + ((long)(0 * 256 + 1)   * 32 + b0) * 1536 + js + jl0;
    const u16* p10 = pre + ((long)(1 * 256 + 255) * 32 + b0) * 1536 + js + jl0;
    const u16* p11 = pre + ((long)(1 * 256 + 254) * 32 + b0) * 1536 + js + jl0;
    pc0.x = *reinterpret_cast<const unsigned*>(p00 + 0 * 384);
    pc0.y = *reinterpret_cast<const unsigned*>(p00 + 1 * 384);
    pc0.z = *reinterpret_cast<const unsigned*>(p00 + 2 * 384);
    pc0.w = *reinterpret_cast<const unsigned*>(p00 + 3 * 384);
    pn0.x = *reinterpret_cast<const unsigned*>(p01 + 0 * 384);
    pn0.y = *reinterpret_cast<const unsigned*>(p01 + 1 * 384);
    pn0.z = *reinterpret_cast<const unsigned*>(p01 + 2 * 384);
    pn0.w = *reinterpret_cast<const unsigned*>(p01 + 3 * 384);
    pc1.x = *reinterpret_cast<const unsigned*>(p10 + 0 * 384);
    pc1.y = *reinterpret_cast<const unsigned*>(p10 + 1 * 384);
    pc1.z = *reinterpret_cast<const unsigned*>(p10 + 2 * 384);
    pc1.w = *reinterpret_cast<const unsigned*>(p10 + 3 * 384);
    pn1.x = *reinterpret_cast<const unsigned*>(p11 + 0 * 384);
    pn1.y = *reinterpret_cast<const unsigned*>(p11 + 1 * 384);
    pn1.z = *reinterpret_cast<const unsigned*>(p11 + 2 * 384);
    pn1.w = *reinterpret_cast<const unsigned*>(p11 + 3 * 384);
  }

  for (int s = 0; s < 256; ++s){
    substep<0>(s, tid, sl, js, wv, l15, l4, b0, q, jl0,
               pre, Y, H64, lw[0], hb, gl2, c00, c01, pc0, pn0);
    substep<1>(s, tid, sl, js, wv, l15, l4, b0, q, jl0,
               pre, Y, H64, lw[1], hb, gl2, c10, c11, pc1, pn1);
  }
}

// ---------- K4: emissions  em[b][t][c] = Y2 @ fc_w^T + fc_b ----------
__global__ __launch_bounds__(256) void fc_em(
    const u16* __restrict__ Y2, const float* __restrict__ fw,
    const float* __restrict__ fb, float* __restrict__ em)
{
  int row = blockIdx.x * 4 + (threadIdx.x >> 6);   // row = t*32+b
  int lane = threadIdx.x & 63;
  float acc[14];
#pragma unroll
  for (int c = 0; c < 14; ++c) acc[c] = 0.f;
#pragma unroll
  for (int u = 0; u < 12; ++u){
    int k = lane + 64 * u;
    float y = b2f(Y2[(long)row * 768 + k]);
#pragma unroll
    for (int c = 0; c < 14; ++c) acc[c] += y * fw[c * 768 + k];
  }
#pragma unroll
  for (int c = 0; c < 14; ++c){
    float a = acc[c];
#pragma unroll
    for (int o = 32; o > 0; o >>= 1) a += __shfl_xor(a, o);
    acc[c] = a;
  }
  if (lane == 0){
    int tt = row >> 5, b = row & 31;
#pragma unroll
    for (int c = 0; c < 14; ++c) em[(long)(b * 256 + tt) * 14 + c] = acc[c] + fb[c];
  }
}

// ---------- K5: CRF per-sequence loss (one wave per b) ----------
__global__ __launch_bounds__(64) void crf_fwd(
    const float* __restrict__ em,   // [32][256][14]
    const int* __restrict__ labels, // [32][256]
    const float* __restrict__ cs, const float* __restrict__ ce,
    const float* __restrict__ ct,   // [14][14]
    float* __restrict__ lossb)
{
  int b = blockIdx.x;
  int lane = threadIdx.x;
  const float* E = em + (long)b * 256 * 14;
  const int* L = labels + b * 256;

  float sc = 0.f;
  for (int t = lane; t < 256; t += 64){
    int lt = L[t];
    sc += E[t * 14 + lt];
    if (t < 255) sc += ct[lt * 14 + L[t + 1]];
  }
#pragma unroll
  for (int o = 32; o > 0; o >>= 1) sc += __shfl_xor(sc, o);
  float score = sc + cs[L[0]] + ce[L[255]];

  __shared__ float al[2][16];
  int j = lane >> 2, ih = lane & 3;
  if (lane < 16){
    al[0][lane] = (lane < 14) ? (cs[lane] + E[lane]) : -1e30f;
    al[1][lane] = -1e30f;
  }
  __syncthreads();
  float tr[4];
#pragma unroll
  for (int w = 0; w < 4; ++w){
    int i = ih * 4 + w;
    tr[w] = (i < 14 && j < 14) ? ct[i * 14 + j] : -1e30f;
  }
  for (int t = 1; t < 256; ++t){
    int par = t & 1;
    float vals[4]; float m = -1e30f;
#pragma unroll
    for (int w = 0; w < 4; ++w){
      int i = ih * 4 + w;
      float v = al[par ^ 1][i] + tr[w];
      vals[w] = v; m = fmaxf(m, v);
    }
    m = fmaxf(m, __shfl_xor(m, 1));
    m = fmaxf(m, __shfl_xor(m, 2));
    float s = 0.f;
#pragma unroll
    for (int w = 0; w < 4; ++w) s += __expf(vals[w] - m);
    s += __shfl_xor(s, 1);
    s += __shfl_xor(s, 2);
    if (ih == 0 && j < 14) al[par][j] = m + __logf(s) + E[t * 14 + j];
    __syncthreads();
  }
  float v = (lane < 14) ? (al[1][lane] + ce[lane]) : -1e30f;
  float mm = v;
#pragma unroll
  for (int o = 32; o > 0; o >>= 1) mm = fmaxf(mm, __shfl_xor(mm, o));
  float ss = (lane < 14) ? __expf(v - mm) : 0.f;
#pragma unroll
  for (int o = 32; o > 0; o >>= 1) ss += __shfl_xor(ss, o);
  if (lane == 0) lossb[b] = (mm + __logf(ss)) - score;
}

// ---------- K6: final sum ----------
__global__ __launch_bounds__(64) void final_sum(const float* __restrict__ lb, float* __restrict__ out){
  int lane = threadIdx.x;
  float v = (lane < 32) ? lb[lane] : 0.f;
#pragma unroll
  for (int o = 32; o > 0; o >>= 1) v += __shfl_xor(v, o);
  if (lane == 0) out[0] = v;
}

// ---------- host ----------
extern "C" void kernel_launch(void* const* d_in, const int* in_sizes, int n_in,
                              void* d_out, int out_size, void* d_ws, size_t ws_size,
                              hipStream_t stream)
{
  const int*   ids = (const int*)d_in[0];
  const int*   lab = (const int*)d_in[1];
  const float* we  = (const float*)d_in[2];
  const float* pe  = (const float*)d_in[3];
  const float* te  = (const float*)d_in[4];
  const float* lng = (const float*)d_in[5];
  const float* lnb = (const float*)d_in[6];
  const float* wih = (const float*)d_in[7];
  const float* whh = (const float*)d_in[8];
  const float* bih = (const float*)d_in[9];
  const float* bhh = (const float*)d_in[10];
  const float* fcw = (const float*)d_in[11];
  const float* fcb = (const float*)d_in[12];
  const float* cs  = (const float*)d_in[13];
  const float* ce  = (const float*)d_in[14];
  const float* ct  = (const float*)d_in[15];
  float* out = (float*)d_out;

  char* ws = (char*)d_ws;
  size_t off = 0;
  u16* X0  = (u16*)(ws + off); off += (size_t)8192 * 768 * 2;          // 12.58 MB
  u16* Y1  = (u16*)(ws + off); off += (size_t)8192 * 768 * 2;          // 12.58 MB
  u16* PRE = (u16*)(ws + off); off += (size_t)2 * 256 * 32 * 1536 * 2; // 50.33 MB
  float* EM = (float*)(ws + off); off += (size_t)32 * 256 * 14 * 4;    // 0.46 MB
  u64* H64a = (u64*)(ws + off); off += (size_t)2 * 2 * 192 * 32 * 8;   // 196 KB
  u64* H64b = (u64*)(ws + off); off += (size_t)2 * 2 * 192 * 32 * 8;   // 196 KB
  float* LB = (float*)(ws + off); off += 128;
  u16* Y2 = X0;   // X0 dead after layer-1 pre-projection

  embed_ln<<<8192, 256, 0, stream>>>(ids, we, pe, te, lng, lnb, X0);

  // layer 0
  gemm_pre<<<dim3(128, 48), 256, 0, stream>>>(X0, wih, bih, bhh, PRE);
  lstm_layer<<<24, 256, 0, stream>>>(whh, PRE, Y1, H64a);
  // layer 1
  gemm_pre<<<dim3(128, 48), 256, 0, stream>>>(Y1, wih + (size_t)2 * 1536 * 768,
                                              bih + 2 * 1536, bhh + 2 * 1536, PRE);
  lstm_layer<<<24, 256, 0, stream>>>(whh + (size_t)2 * 1536 * 384, PRE, Y2, H64b);

  fc_em<<<2048, 256, 0, stream>>>(Y2, fcw, fcb, EM);
  crf_fwd<<<32, 64, 0, stream>>>(EM, lab, cs, ce, ct, LB);
  final_sum<<<1, 64, 0, stream>>>(LB, out);
}

// Round 10
// 2528.740 us; speedup vs baseline: 2.5795x; 2.5795x over previous
//
#include <hip/hip_runtime.h>

typedef unsigned short u16;
typedef unsigned long long u64;
typedef __bf16 bfx8 __attribute__((ext_vector_type(8)));
typedef float  fx4  __attribute__((ext_vector_type(4)));

// ---------- helpers ----------
static __device__ __forceinline__ float b2f(u16 u){
  unsigned v = ((unsigned)u) << 16;
  return __builtin_bit_cast(float, v);
}
static __device__ __forceinline__ u16 f2b(float f){
  unsigned u = __builtin_bit_cast(unsigned, f);
  u = (u + 0x7FFFu + ((u >> 16) & 1u)) >> 16;
  return (u16)u;
}
static __device__ __forceinline__ float blo(unsigned v){ return b2f((u16)(v & 0xFFFFu)); }
static __device__ __forceinline__ float bhi(unsigned v){ return b2f((u16)(v >> 16)); }
static __device__ __forceinline__ float sigm(float x){
  float cx = fminf(fmaxf(x, -30.f), 30.f);
  float e = __expf(-cx);
  return __builtin_amdgcn_rcpf(1.f + e);
}
static __device__ __forceinline__ float tanh_f(float x){
  float cx = fminf(fmaxf(x, -15.f), 15.f);
  float e = __expf(2.f * cx);
  return (e - 1.f) * __builtin_amdgcn_rcpf(e + 1.f);
}
// relaxed agent-scope 8B atomics (coherent at L3, no fences)
static __device__ __forceinline__ u64 ald64(const u64* p){
  return __hip_atomic_load(p, __ATOMIC_RELAXED, __HIP_MEMORY_SCOPE_AGENT);
}
static __device__ __forceinline__ void ast64(u64* p, u64 v){
  __hip_atomic_store(p, v, __ATOMIC_RELAXED, __HIP_MEMORY_SCOPE_AGENT);
}

// ---------- K1: embeddings + LayerNorm -> X (bf16, [T*32+b][768]) ----------
__global__ __launch_bounds__(256) void embed_ln(
    const int* __restrict__ ids, const float* __restrict__ we,
    const float* __restrict__ pe, const float* __restrict__ te,
    const float* __restrict__ lng, const float* __restrict__ lnb,
    u16* __restrict__ X)
{
  int row = blockIdx.x;            // row = t*32 + b
  int t = row >> 5, b = row & 31;
  int id = ids[b * 256 + t];
  int tid = threadIdx.x;
  int wv = tid >> 6, lane = tid & 63;
  __shared__ float red[8];
  float v[3]; float s = 0.f, s2 = 0.f;
  const float* wrow = we + (long)id * 768;
  const float* prow = pe + (long)t * 768;
#pragma unroll
  for (int u = 0; u < 3; ++u){
    int k = tid + 256 * u;
    float x = wrow[k] + prow[k] + te[k];
    v[u] = x; s += x; s2 += x * x;
  }
#pragma unroll
  for (int o = 32; o > 0; o >>= 1){ s += __shfl_xor(s, o); s2 += __shfl_xor(s2, o); }
  if (lane == 0){ red[wv] = s; red[4 + wv] = s2; }
  __syncthreads();
  float S  = red[0] + red[1] + red[2] + red[3];
  float S2 = red[4] + red[5] + red[6] + red[7];
  float mu = S * (1.f / 768.f);
  float var = S2 * (1.f / 768.f) - mu * mu;
  float rs = rsqrtf(var + 1e-12f);
#pragma unroll
  for (int u = 0; u < 3; ++u){
    int k = tid + 256 * u;
    float y = (v[u] - mu) * rs * lng[k] + lnb[k];
    X[(long)row * 768 + k] = f2b(y);
  }
}

// ---------- convert one layer's W_ih (f32 -> bf16), 4 elems/thread ----------
__global__ __launch_bounds__(256) void conv_wih(
    const float* __restrict__ w, u16* __restrict__ o)
{
  long i = ((long)blockIdx.x * 256 + threadIdx.x) * 4;   // 2*1536*768 total
  float4 v = *reinterpret_cast<const float4*>(&w[i]);
  short4 pk;
  pk.x = (short)f2b(v.x); pk.y = (short)f2b(v.y);
  pk.z = (short)f2b(v.z); pk.w = (short)f2b(v.w);
  *reinterpret_cast<short4*>(&o[i]) = pk;
}

// ---------- K2: pre-projection GEMM  PRE[d][t][b][1536] = (A @ Wih^T + bias) ----------
__global__ __launch_bounds__(256) void gemm_pre(
    const u16* __restrict__ A,      // [8192][768] bf16, row = t*32+b
    const u16* __restrict__ W,      // [3072][768] bf16 (pre-converted, both dirs)
    const float* __restrict__ bi,
    const float* __restrict__ bh,
    u16* __restrict__ pre)          // [2][256][32][1536] bf16
{
  __shared__ u16 la[64][40];
  __shared__ u16 lb[64][40];
  int m0 = blockIdx.x * 64, n0 = blockIdx.y * 64;
  int tid = threadIdx.x;
  int wv = tid >> 6, lane = tid & 63;
  int l15 = lane & 15, l4 = lane >> 4;
  int r = tid >> 2, seg = (tid & 3) * 8;
  fx4 acc[4];
#pragma unroll
  for (int i = 0; i < 4; ++i){ acc[i][0]=0.f; acc[i][1]=0.f; acc[i][2]=0.f; acc[i][3]=0.f; }
  for (int k0 = 0; k0 < 768; k0 += 32){
    __syncthreads();
    *reinterpret_cast<uint4*>(&la[r][seg]) =
        *reinterpret_cast<const uint4*>(&A[(long)(m0 + r) * 768 + k0 + seg]);
    *reinterpret_cast<uint4*>(&lb[r][seg]) =
        *reinterpret_cast<const uint4*>(&W[(long)(n0 + r) * 768 + k0 + seg]);
    __syncthreads();
    bfx8 af = __builtin_bit_cast(bfx8, *reinterpret_cast<const uint4*>(&la[wv * 16 + l15][8 * l4]));
#pragma unroll
    for (int nt = 0; nt < 4; ++nt){
      bfx8 bf = __builtin_bit_cast(bfx8, *reinterpret_cast<const uint4*>(&lb[nt * 16 + l15][8 * l4]));
      acc[nt] = __builtin_amdgcn_mfma_f32_16x16x32_bf16(af, bf, acc[nt], 0, 0, 0);
    }
  }
#pragma unroll
  for (int nt = 0; nt < 4; ++nt){
    int n = n0 + nt * 16 + l15;
    int d = (n >= 1536) ? 1 : 0;
    int np = n - d * 1536;
    float bias = bi[n] + bh[n];
#pragma unroll
    for (int q = 0; q < 4; ++q){
      int m = m0 + wv * 16 + 4 * l4 + q;
      int tt = m >> 5, bb = m & 31;
      float vv = acc[nt][q] + bias;
      pre[((long)((d * 256 + tt) * 32 + bb)) * 1536 + np] = f2b(vv);
    }
  }
}

// ---------- K3: one bidirectional LSTM layer (48 WGs, dataflow-synced) ----------
// WG wg: dir d = wg/24, hidden slice js = (wg%24)*16.
// H64: [2 parity][2 dir][192 dimpair][32 b]; u64 = {tag:high32, h_odd:hi16, h_even:lo16}
__global__ __launch_bounds__(256) void lstm_layer(
    const float* __restrict__ Whh,  // [2][1536][384] f32 this layer
    const u16*  __restrict__ pre,   // [2][256][32][1536] bf16
    u16* __restrict__ Y,            // [256][32][768] bf16
    u64* __restrict__ H64)
{
  __shared__ u16 lw[64][386];        // W slice bf16, XOR-swizzled cols
  __shared__ u16 hb[32][386];        // staged h, XOR-swizzled cols
  __shared__ float gl2[4][16][33];   // [gate][jl][b^swz]
  int wg = blockIdx.x;
  int d = wg / 24, sl = wg - d * 24;
  int js = sl * 16;
  int tid = threadIdx.x;
  int wv = tid >> 6, lane = tid & 63;
  int l15 = lane & 15, l4 = lane >> 4;
  int b0 = tid & 31, q = tid >> 5;   // q 0..7
  int jl0 = 2 * q, jl1 = 2 * q + 1;

  // 1) publish own h_{-1} slice first: parity 1, tag 0, h = 0
  ast64(&H64[((long)(1 * 2 + d) * 192 + sl * 8 + q) * 32 + b0], 0ull);
  u64 own_word = 0ull;               // last word this thread published

  // 2) stage Whh slice -> lw (f32 -> bf16, swizzled), float4 loads
  for (int i = tid; i < 64 * 96; i += 256){
    int rr = i / 96, c4 = i - rr * 96;
    const float* src = Whh + ((long)(d * 1536 + (rr >> 4) * 384 + js + (rr & 15))) * 384 + 4 * c4;
    float4 v = *reinterpret_cast<const float4*>(src);
    short4 pk;
    pk.x = (short)f2b(v.x); pk.y = (short)f2b(v.y);
    pk.z = (short)f2b(v.z); pk.w = (short)f2b(v.w);
    *reinterpret_cast<short4*>(&lw[rr][(4 * c4) ^ (8 * (rr & 7))]) = pk;
  }
  __syncthreads();

  float c0 = 0.f, c1 = 0.f;

  // prefetch pre for s=0 and s=1 (distance-2 pipeline)
  int t0 = d ? 255 : 0;
  int t1 = d ? 254 : 1;
  const u16* pb0 = pre + ((long)(d * 256 + t0) * 32 + b0) * 1536 + js + jl0;
  const u16* pb1 = pre + ((long)(d * 256 + t1) * 32 + b0) * 1536 + js + jl0;
  uint4 pc, pn;
  pc.x = *reinterpret_cast<const unsigned*>(pb0 + 0 * 384);
  pc.y = *reinterpret_cast<const unsigned*>(pb0 + 1 * 384);
  pc.z = *reinterpret_cast<const unsigned*>(pb0 + 2 * 384);
  pc.w = *reinterpret_cast<const unsigned*>(pb0 + 3 * 384);
  pn.x = *reinterpret_cast<const unsigned*>(pb1 + 0 * 384);
  pn.y = *reinterpret_cast<const unsigned*>(pb1 + 1 * 384);
  pn.z = *reinterpret_cast<const unsigned*>(pb1 + 2 * 384);
  pn.w = *reinterpret_cast<const unsigned*>(pb1 + 3 * 384);

  for (int s = 0; s < 256; ++s){
    int tt = d ? (255 - s) : s;
    int pr = (s + 1) & 1;            // read parity (holds h_{s-1}, tag s)
    int pw = s & 1;                  // write parity (h_s, tag s+1)

    // ---- stage h_{s-1}: batch-parallel tag-poll, COMMIT-ON-SUCCESS.
    //      Retry passes: 24 parallel L3 loads + tag check + barrier-and only
    //      (no LDS writes -> shorter pass period, ~3x fewer bank conflicts).
    //      Own entry replaced from register via UNROLLED conditional moves
    //      (static index; R5's vb[sl]= spilled the array to scratch). ----
    {
      const u64* hsrc = H64 + (long)(pr * 2 + d) * 192 * 32;
      unsigned tagv = (unsigned)s;
      __builtin_amdgcn_s_sleep(2);   // settle: let publishes land in L3
      u64 vb[24];
      for (;;){
#pragma unroll
        for (int i = 0; i < 24; ++i) vb[i] = ald64(&hsrc[tid + 256 * i]);
#pragma unroll
        for (int i = 0; i < 24; ++i) if (i == sl) vb[i] = own_word;  // static idx
        bool ok = true;
#pragma unroll
        for (int i = 0; i < 24; ++i) ok = ok && ((unsigned)(vb[i] >> 32) == tagv);
        if (__syncthreads_and((int)ok)) break;
      }
#pragma unroll
      for (int i = 0; i < 24; ++i){
        int f = tid + 256 * i;
        int bb = f & 31, j2 = f >> 5;
        *reinterpret_cast<unsigned*>(&hb[bb][(2 * j2) ^ (8 * (bb & 7))]) = (unsigned)vb[i];
      }
      __syncthreads();
    }

    // issue pre prefetch for s+2 AFTER poll (never inside a poll vmcnt window)
    int s2 = (s + 2 < 256) ? (s + 2) : 255;
    int t2 = d ? (255 - s2) : s2;
    const u16* pb2 = pre + ((long)(d * 256 + t2) * 32 + b0) * 1536 + js + jl0;
    uint4 p2;
    p2.x = *reinterpret_cast<const unsigned*>(pb2 + 0 * 384);
    p2.y = *reinterpret_cast<const unsigned*>(pb2 + 1 * 384);
    p2.z = *reinterpret_cast<const unsigned*>(pb2 + 2 * 384);
    p2.w = *reinterpret_cast<const unsigned*>(pb2 + 3 * 384);

    // ---- MFMA: gates(g=wv, b, jl=l15) over K=384, two interleaved chains ----
    fx4 a0a, a0b, a1a, a1b;
#pragma unroll
    for (int z = 0; z < 4; ++z){ a0a[z]=0.f; a0b[z]=0.f; a1a[z]=0.f; a1b[z]=0.f; }
#pragma unroll
    for (int kk = 0; kk < 12; kk += 2){
      int col0 = (kk * 32 + 8 * l4) ^ (8 * (l15 & 7));
      int col1 = ((kk + 1) * 32 + 8 * l4) ^ (8 * (l15 & 7));
      bfx8 bw0 = __builtin_bit_cast(bfx8, *reinterpret_cast<const uint4*>(&lw[wv * 16 + l15][col0]));
      bfx8 h00 = __builtin_bit_cast(bfx8, *reinterpret_cast<const uint4*>(&hb[l15][col0]));
      bfx8 h10 = __builtin_bit_cast(bfx8, *reinterpret_cast<const uint4*>(&hb[16 + l15][col0]));
      bfx8 bw1 = __builtin_bit_cast(bfx8, *reinterpret_cast<const uint4*>(&lw[wv * 16 + l15][col1]));
      bfx8 h01 = __builtin_bit_cast(bfx8, *reinterpret_cast<const uint4*>(&hb[l15][col1]));
      bfx8 h11 = __builtin_bit_cast(bfx8, *reinterpret_cast<const uint4*>(&hb[16 + l15][col1]));
      a0a = __builtin_amdgcn_mfma_f32_16x16x32_bf16(h00, bw0, a0a, 0, 0, 0);
      a1a = __builtin_amdgcn_mfma_f32_16x16x32_bf16(h10, bw0, a1a, 0, 0, 0);
      a0b = __builtin_amdgcn_mfma_f32_16x16x32_bf16(h01, bw1, a0b, 0, 0, 0);
      a1b = __builtin_amdgcn_mfma_f32_16x16x32_bf16(h11, bw1, a1b, 0, 0, 0);
    }
#pragma unroll
    for (int qq = 0; qq < 4; ++qq){
      int bb0 = (4 * l4 + qq) ^ (4 * (l15 & 7));
      int bb1 = (16 + 4 * l4 + qq) ^ (4 * (l15 & 7));
      gl2[wv][l15][bb0] = a0a[qq] + a0b[qq];
      gl2[wv][l15][bb1] = a1a[qq] + a1b[qq];
    }
    __syncthreads();

    // ---- gates + cell update (2 adjacent hidden dims per thread) ----
    int x0 = b0 ^ (4 * (jl0 & 7));
    int x1 = b0 ^ (4 * (jl1 & 7));
    float gi0 = gl2[0][jl0][x0] + blo(pc.x), gi1 = gl2[0][jl1][x1] + bhi(pc.x);
    float gf0 = gl2[1][jl0][x0] + blo(pc.y), gf1 = gl2[1][jl1][x1] + bhi(pc.y);
    float gg0 = gl2[2][jl0][x0] + blo(pc.z), gg1 = gl2[2][jl1][x1] + bhi(pc.z);
    float go0 = gl2[3][jl0][x0] + blo(pc.w), go1 = gl2[3][jl1][x1] + bhi(pc.w);
    c0 = sigm(gf0) * c0 + sigm(gi0) * tanh_f(gg0);
    float h0 = sigm(go0) * tanh_f(c0);
    c1 = sigm(gf1) * c1 + sigm(gi1) * tanh_f(gg1);
    float h1 = sigm(go1) * tanh_f(c1);

    unsigned hv = (unsigned)f2b(h0) | ((unsigned)f2b(h1) << 16);
    own_word = ((u64)(unsigned)(s + 1) << 32) | (u64)hv;
    // fire-and-forget publish: {tag s+1, h pair}
    ast64(&H64[((long)(pw * 2 + d) * 192 + sl * 8 + q) * 32 + b0], own_word);
    // layer output (plain u32 store)
    *reinterpret_cast<unsigned*>(&Y[((long)tt * 32 + b0) * 768 + d * 384 + js + jl0]) = hv;
    pc = pn; pn = p2;
  }
}

// ---------- K4: emissions  em[b][t][c] = Y2 @ fc_w^T + fc_b ----------
__global__ __launch_bounds__(256) void fc_em(
    const u16* __restrict__ Y2, const float* __restrict__ fw,
    const float* __restrict__ fb, float* __restrict__ em)
{
  int row = blockIdx.x * 4 + (threadIdx.x >> 6);   // row = t*32+b
  int lane = threadIdx.x & 63;
  float acc[14];
#pragma unroll
  for (int c = 0; c < 14; ++c) acc[c] = 0.f;
#pragma unroll
  for (int u = 0; u < 12; ++u){
    int k = lane + 64 * u;
    float y = b2f(Y2[(long)row * 768 + k]);
#pragma unroll
    for (int c = 0; c < 14; ++c) acc[c] += y * fw[c * 768 + k];
  }
#pragma unroll
  for (int c = 0; c < 14; ++c){
    float a = acc[c];
#pragma unroll
    for (int o = 32; o > 0; o >>= 1) a += __shfl_xor(a, o);
    acc[c] = a;
  }
  if (lane == 0){
    int tt = row >> 5, b = row & 31;
#pragma unroll
    for (int c = 0; c < 14; ++c) em[(long)(b * 256 + tt) * 14 + c] = acc[c] + fb[c];
  }
}

// ---------- K5: CRF per-sequence loss (one wave per b) ----------
__global__ __launch_bounds__(64) void crf_fwd(
    const float* __restrict__ em,   // [32][256][14]
    const int* __restrict__ labels, // [32][256]
    const float* __restrict__ cs, const float* __restrict__ ce,
    const float* __restrict__ ct,   // [14][14]
    float* __restrict__ lossb)
{
  int b = blockIdx.x;
  int lane = threadIdx.x;
  const float* E = em + (long)b * 256 * 14;
  const int* L = labels + b * 256;

  float sc = 0.f;
  for (int t = lane; t < 256; t += 64){
    int lt = L[t];
    sc += E[t * 14 + lt];
    if (t < 255) sc += ct[lt * 14 + L[t + 1]];
  }
#pragma unroll
  for (int o = 32; o > 0; o >>= 1) sc += __shfl_xor(sc, o);
  float score = sc + cs[L[0]] + ce[L[255]];

  __shared__ float al[2][16];
  int j = lane >> 2, ih = lane & 3;
  if (lane < 16){
    al[0][lane] = (lane < 14) ? (cs[lane] + E[lane]) : -1e30f;
    al[1][lane] = -1e30f;
  }
  __syncthreads();
  float tr[4];
#pragma unroll
  for (int w = 0; w < 4; ++w){
    int i = ih * 4 + w;
    tr[w] = (i < 14 && j < 14) ? ct[i * 14 + j] : -1e30f;
  }
  for (int t = 1; t < 256; ++t){
    int par = t & 1;
    float vals[4]; float m = -1e30f;
#pragma unroll
    for (int w = 0; w < 4; ++w){
      int i = ih * 4 + w;
      float v = al[par ^ 1][i] + tr[w];
      vals[w] = v; m = fmaxf(m, v);
    }
    m = fmaxf(m, __shfl_xor(m, 1));
    m = fmaxf(m, __shfl_xor(m, 2));
    float s = 0.f;
#pragma unroll
    for (int w = 0; w < 4; ++w) s += __expf(vals[w] - m);
    s += __shfl_xor(s, 1);
    s += __shfl_xor(s, 2);
    if (ih == 0 && j < 14) al[par][j] = m + __logf(s) + E[t * 14 + j];
    __syncthreads();
  }
  float v = (lane < 14) ? (al[1][lane] + ce[lane]) : -1e30f;
  float mm = v;
#pragma unroll
  for (int o = 32; o > 0; o >>= 1) mm = fmaxf(mm, __shfl_xor(mm, o));
  float ss = (lane < 14) ? __expf(v - mm) : 0.f;
#pragma unroll
  for (int o = 32; o > 0; o >>= 1) ss += __shfl_xor(ss, o);
  if (lane == 0) lossb[b] = (mm + __logf(ss)) - score;
}

// ---------- K6: final sum ----------
__global__ __launch_bounds__(64) void final_sum(const float* __restrict__ lb, float* __restrict__ out){
  int lane = threadIdx.x;
  float v = (lane < 32) ? lb[lane] : 0.f;
#pragma unroll
  for (int o = 32; o > 0; o >>= 1) v += __shfl_xor(v, o);
  if (lane == 0) out[0] = v;
}

// ---------- host ----------
extern "C" void kernel_launch(void* const* d_in, const int* in_sizes, int n_in,
                              void* d_out, int out_size, void* d_ws, size_t ws_size,
                              hipStream_t stream)
{
  const int*   ids = (const int*)d_in[0];
  const int*   lab = (const int*)d_in[1];
  const float* we  = (const float*)d_in[2];
  const float* pe  = (const float*)d_in[3];
  const float* te  = (const float*)d_in[4];
  const float* lng = (const float*)d_in[5];
  const float* lnb = (const float*)d_in[6];
  const float* wih = (const float*)d_in[7];
  const float* whh = (const float*)d_in[8];
  const float* bih = (const float*)d_in[9];
  const float* bhh = (const float*)d_in[10];
  const float* fcw = (const float*)d_in[11];
  const float* fcb = (const float*)d_in[12];
  const float* cs  = (const float*)d_in[13];
  const float* ce  = (const float*)d_in[14];
  const float* ct  = (const float*)d_in[15];
  float* out = (float*)d_out;

  char* ws = (char*)d_ws;
  size_t off = 0;
  u16* X0  = (u16*)(ws + off); off += (size_t)8192 * 768 * 2;          // 12.58 MB
  u16* Y1  = (u16*)(ws + off); off += (size_t)8192 * 768 * 2;          // 12.58 MB
  u16* PRE = (u16*)(ws + off); off += (size_t)2 * 256 * 32 * 1536 * 2; // 50.33 MB
  float* EM = (float*)(ws + off); off += (size_t)32 * 256 * 14 * 4;    // 0.46 MB
  u64* H64a = (u64*)(ws + off); off += (size_t)2 * 2 * 192 * 32 * 8;   // 196 KB
  u64* H64b = (u64*)(ws + off); off += (size_t)2 * 2 * 192 * 32 * 8;   // 196 KB
  u16* WIHB = (u16*)(ws + off); off += (size_t)2 * 1536 * 768 * 2;     // 4.72 MB
  float* LB = (float*)(ws + off); off += 128;
  u16* Y2 = X0;   // X0 dead after layer-1 pre-projection

  embed_ln<<<8192, 256, 0, stream>>>(ids, we, pe, te, lng, lnb, X0);

  // layer 0
  conv_wih<<<2304, 256, 0, stream>>>(wih, WIHB);
  gemm_pre<<<dim3(128, 48), 256, 0, stream>>>(X0, WIHB, bih, bhh, PRE);
  lstm_layer<<<48, 256, 0, stream>>>(whh, PRE, Y1, H64a);
  // layer 1
  conv_wih<<<2304, 256, 0, stream>>>(wih + (size_t)2 * 1536 * 768, WIHB);
  gemm_pre<<<dim3(128, 48), 256, 0, stream>>>(Y1, WIHB, bih + 2 * 1536,
                                              bhh + 2 * 1536, PRE);
  lstm_layer<<<48, 256, 0, stream>>>(whh + (size_t)2 * 1536 * 384, PRE, Y2, H64b);

  fc_em<<<2048, 256, 0, stream>>>(Y2, fcw, fcb, EM);
  crf_fwd<<<32, 64, 0, stream>>>(EM, lab, cs, ce, ct, LB);
  final_sum<<<1, 64, 0, stream>>>(LB, out);
}

// Round 11
// 2388.603 us; speedup vs baseline: 2.7308x; 1.0587x over previous
//
#include <hip/hip_runtime.h>

typedef unsigned short u16;
typedef unsigned long long u64;
typedef __bf16 bfx8 __attribute__((ext_vector_type(8)));
typedef float  fx4  __attribute__((ext_vector_type(4)));

// ---------- helpers ----------
static __device__ __forceinline__ float b2f(u16 u){
  unsigned v = ((unsigned)u) << 16;
  return __builtin_bit_cast(float, v);
}
static __device__ __forceinline__ u16 f2b(float f){
  unsigned u = __builtin_bit_cast(unsigned, f);
  u = (u + 0x7FFFu + ((u >> 16) & 1u)) >> 16;
  return (u16)u;
}
static __device__ __forceinline__ float blo(unsigned v){ return b2f((u16)(v & 0xFFFFu)); }
static __device__ __forceinline__ float bhi(unsigned v){ return b2f((u16)(v >> 16)); }
static __device__ __forceinline__ float sigm(float x){
  float cx = fminf(fmaxf(x, -30.f), 30.f);
  float e = __expf(-cx);
  return __builtin_amdgcn_rcpf(1.f + e);
}
static __device__ __forceinline__ float tanh_f(float x){
  float cx = fminf(fmaxf(x, -15.f), 15.f);
  float e = __expf(2.f * cx);
  return (e - 1.f) * __builtin_amdgcn_rcpf(e + 1.f);
}
// relaxed agent-scope 8B atomics (coherent at L3, no fences)
static __device__ __forceinline__ u64 ald64(const u64* p){
  return __hip_atomic_load(p, __ATOMIC_RELAXED, __HIP_MEMORY_SCOPE_AGENT);
}
static __device__ __forceinline__ void ast64(u64* p, u64 v){
  __hip_atomic_store(p, v, __ATOMIC_RELAXED, __HIP_MEMORY_SCOPE_AGENT);
}

// ---------- K1: embeddings + LayerNorm -> X (bf16, [T*32+b][768]) ----------
__global__ __launch_bounds__(256) void embed_ln(
    const int* __restrict__ ids, const float* __restrict__ we,
    const float* __restrict__ pe, const float* __restrict__ te,
    const float* __restrict__ lng, const float* __restrict__ lnb,
    u16* __restrict__ X)
{
  int row = blockIdx.x;            // row = t*32 + b
  int t = row >> 5, b = row & 31;
  int id = ids[b * 256 + t];
  int tid = threadIdx.x;
  int wv = tid >> 6, lane = tid & 63;
  __shared__ float red[8];
  float v[3]; float s = 0.f, s2 = 0.f;
  const float* wrow = we + (long)id * 768;
  const float* prow = pe + (long)t * 768;
#pragma unroll
  for (int u = 0; u < 3; ++u){
    int k = tid + 256 * u;
    float x = wrow[k] + prow[k] + te[k];
    v[u] = x; s += x; s2 += x * x;
  }
#pragma unroll
  for (int o = 32; o > 0; o >>= 1){ s += __shfl_xor(s, o); s2 += __shfl_xor(s2, o); }
  if (lane == 0){ red[wv] = s; red[4 + wv] = s2; }
  __syncthreads();
  float S  = red[0] + red[1] + red[2] + red[3];
  float S2 = red[4] + red[5] + red[6] + red[7];
  float mu = S * (1.f / 768.f);
  float var = S2 * (1.f / 768.f) - mu * mu;
  float rs = rsqrtf(var + 1e-12f);
#pragma unroll
  for (int u = 0; u < 3; ++u){
    int k = tid + 256 * u;
    float y = (v[u] - mu) * rs * lng[k] + lnb[k];
    X[(long)row * 768 + k] = f2b(y);
  }
}

// ---------- convert BOTH layers' W_ih (f32 -> bf16), 4 elems/thread ----------
__global__ __launch_bounds__(256) void conv_wih(
    const float* __restrict__ w, u16* __restrict__ o)
{
  long i = ((long)blockIdx.x * 256 + threadIdx.x) * 4;   // 2*2*1536*768 total
  float4 v = *reinterpret_cast<const float4*>(&w[i]);
  short4 pk;
  pk.x = (short)f2b(v.x); pk.y = (short)f2b(v.y);
  pk.z = (short)f2b(v.z); pk.w = (short)f2b(v.w);
  *reinterpret_cast<short4*>(&o[i]) = pk;
}

// ---------- K2: pre-projection GEMM  PRE[d][t][b][1536] = (A @ Wih^T + bias) ----------
__global__ __launch_bounds__(256) void gemm_pre(
    const u16* __restrict__ A,      // [8192][768] bf16, row = t*32+b
    const u16* __restrict__ W,      // [3072][768] bf16 (pre-converted, both dirs)
    const float* __restrict__ bi,
    const float* __restrict__ bh,
    u16* __restrict__ pre)          // [2][256][32][1536] bf16
{
  __shared__ u16 la[64][40];
  __shared__ u16 lb[64][40];
  int m0 = blockIdx.x * 64, n0 = blockIdx.y * 64;
  int tid = threadIdx.x;
  int wv = tid >> 6, lane = tid & 63;
  int l15 = lane & 15, l4 = lane >> 4;
  int r = tid >> 2, seg = (tid & 3) * 8;
  fx4 acc[4];
#pragma unroll
  for (int i = 0; i < 4; ++i){ acc[i][0]=0.f; acc[i][1]=0.f; acc[i][2]=0.f; acc[i][3]=0.f; }
  for (int k0 = 0; k0 < 768; k0 += 32){
    __syncthreads();
    *reinterpret_cast<uint4*>(&la[r][seg]) =
        *reinterpret_cast<const uint4*>(&A[(long)(m0 + r) * 768 + k0 + seg]);
    *reinterpret_cast<uint4*>(&lb[r][seg]) =
        *reinterpret_cast<const uint4*>(&W[(long)(n0 + r) * 768 + k0 + seg]);
    __syncthreads();
    bfx8 af = __builtin_bit_cast(bfx8, *reinterpret_cast<const uint4*>(&la[wv * 16 + l15][8 * l4]));
#pragma unroll
    for (int nt = 0; nt < 4; ++nt){
      bfx8 bf = __builtin_bit_cast(bfx8, *reinterpret_cast<const uint4*>(&lb[nt * 16 + l15][8 * l4]));
      acc[nt] = __builtin_amdgcn_mfma_f32_16x16x32_bf16(af, bf, acc[nt], 0, 0, 0);
    }
  }
#pragma unroll
  for (int nt = 0; nt < 4; ++nt){
    int n = n0 + nt * 16 + l15;
    int d = (n >= 1536) ? 1 : 0;
    int np = n - d * 1536;
    float bias = bi[n] + bh[n];
#pragma unroll
    for (int q = 0; q < 4; ++q){
      int m = m0 + wv * 16 + 4 * l4 + q;
      int tt = m >> 5, bb = m & 31;
      float vv = acc[nt][q] + bias;
      pre[((long)((d * 256 + tt) * 32 + bb)) * 1536 + np] = f2b(vv);
    }
  }
}

// ---------- K3: one bidirectional LSTM layer (48 WGs, dataflow-synced) ----------
// EXACT R6 structure (measured 1052 us): commit-every-pass tag-poll,
// register self-skip via unrolled static-index conditional moves.
// H64: [2 parity][2 dir][192 dimpair][32 b]; u64 = {tag:high32, h pair:low32}
__global__ __launch_bounds__(256) void lstm_layer(
    const float* __restrict__ Whh,  // [2][1536][384] f32 this layer
    const u16*  __restrict__ pre,   // [2][256][32][1536] bf16
    u16* __restrict__ Y,            // [256][32][768] bf16
    u64* __restrict__ H64)
{
  __shared__ u16 lw[64][386];        // W slice bf16, XOR-swizzled cols
  __shared__ u16 hb[32][386];        // staged h, XOR-swizzled cols
  __shared__ float gl2[4][16][33];   // [gate][jl][b^swz]
  int wg = blockIdx.x;
  int d = wg / 24, sl = wg - d * 24;
  int js = sl * 16;
  int tid = threadIdx.x;
  int wv = tid >> 6, lane = tid & 63;
  int l15 = lane & 15, l4 = lane >> 4;
  int b0 = tid & 31, q = tid >> 5;   // q 0..7
  int jl0 = 2 * q, jl1 = 2 * q + 1;

  // 1) publish own h_{-1} slice first: parity 1, tag 0, h = 0
  ast64(&H64[((long)(1 * 2 + d) * 192 + sl * 8 + q) * 32 + b0], 0ull);
  u64 own_word = 0ull;               // last word this thread published

  // 2) stage Whh slice -> lw (f32 -> bf16, swizzled), float4 loads
  for (int i = tid; i < 64 * 96; i += 256){
    int rr = i / 96, c4 = i - rr * 96;
    const float* src = Whh + ((long)(d * 1536 + (rr >> 4) * 384 + js + (rr & 15))) * 384 + 4 * c4;
    float4 v = *reinterpret_cast<const float4*>(src);
    short4 pk;
    pk.x = (short)f2b(v.x); pk.y = (short)f2b(v.y);
    pk.z = (short)f2b(v.z); pk.w = (short)f2b(v.w);
    *reinterpret_cast<short4*>(&lw[rr][(4 * c4) ^ (8 * (rr & 7))]) = pk;
  }
  __syncthreads();

  float c0 = 0.f, c1 = 0.f;

  // prefetch pre for s=0 and s=1 (distance-2 pipeline)
  int t0 = d ? 255 : 0;
  int t1 = d ? 254 : 1;
  const u16* pb0 = pre + ((long)(d * 256 + t0) * 32 + b0) * 1536 + js + jl0;
  const u16* pb1 = pre + ((long)(d * 256 + t1) * 32 + b0) * 1536 + js + jl0;
  uint4 pc, pn;
  pc.x = *reinterpret_cast<const unsigned*>(pb0 + 0 * 384);
  pc.y = *reinterpret_cast<const unsigned*>(pb0 + 1 * 384);
  pc.z = *reinterpret_cast<const unsigned*>(pb0 + 2 * 384);
  pc.w = *reinterpret_cast<const unsigned*>(pb0 + 3 * 384);
  pn.x = *reinterpret_cast<const unsigned*>(pb1 + 0 * 384);
  pn.y = *reinterpret_cast<const unsigned*>(pb1 + 1 * 384);
  pn.z = *reinterpret_cast<const unsigned*>(pb1 + 2 * 384);
  pn.w = *reinterpret_cast<const unsigned*>(pb1 + 3 * 384);

  for (int s = 0; s < 256; ++s){
    int tt = d ? (255 - s) : s;
    int pr = (s + 1) & 1;            // read parity (holds h_{s-1}, tag s)
    int pw = s & 1;                  // write parity (h_s, tag s+1)

    // ---- stage h_{s-1}: batch-parallel poll, commit every pass (R6) ----
    {
      const u64* hsrc = H64 + (long)(pr * 2 + d) * 192 * 32;
      unsigned tagv = (unsigned)s;
      __builtin_amdgcn_s_sleep(2);   // settle: let publishes land in L3
      for (;;){
        u64 vb[24];
#pragma unroll
        for (int i = 0; i < 24; ++i) vb[i] = ald64(&hsrc[tid + 256 * i]);
#pragma unroll
        for (int i = 0; i < 24; ++i) if (i == sl) vb[i] = own_word;  // static idx
        bool ok = true;
#pragma unroll
        for (int i = 0; i < 24; ++i) ok = ok && ((unsigned)(vb[i] >> 32) == tagv);
#pragma unroll
        for (int i = 0; i < 24; ++i){
          int f = tid + 256 * i;
          int bb = f & 31, j2 = f >> 5;
          *reinterpret_cast<unsigned*>(&hb[bb][(2 * j2) ^ (8 * (bb & 7))]) = (unsigned)vb[i];
        }
        if (__syncthreads_and((int)ok)) break;
      }
    }

    // issue pre prefetch for s+2 AFTER poll (never inside a poll vmcnt window)
    int s2 = (s + 2 < 256) ? (s + 2) : 255;
    int t2 = d ? (255 - s2) : s2;
    const u16* pb2 = pre + ((long)(d * 256 + t2) * 32 + b0) * 1536 + js + jl0;
    uint4 p2;
    p2.x = *reinterpret_cast<const unsigned*>(pb2 + 0 * 384);
    p2.y = *reinterpret_cast<const unsigned*>(pb2 + 1 * 384);
    p2.z = *reinterpret_cast<const unsigned*>(pb2 + 2 * 384);
    p2.w = *reinterpret_cast<const unsigned*>(pb2 + 3 * 384);

    // ---- MFMA: gates(g=wv, b, jl=l15) over K=384, two interleaved chains ----
    fx4 a0a, a0b, a1a, a1b;
#pragma unroll
    for (int z = 0; z < 4; ++z){ a0a[z]=0.f; a0b[z]=0.f; a1a[z]=0.f; a1b[z]=0.f; }
#pragma unroll
    for (int kk = 0; kk < 12; kk += 2){
      int col0 = (kk * 32 + 8 * l4) ^ (8 * (l15 & 7));
      int col1 = ((kk + 1) * 32 + 8 * l4) ^ (8 * (l15 & 7));
      bfx8 bw0 = __builtin_bit_cast(bfx8, *reinterpret_cast<const uint4*>(&lw[wv * 16 + l15][col0]));
      bfx8 h00 = __builtin_bit_cast(bfx8, *reinterpret_cast<const uint4*>(&hb[l15][col0]));
      bfx8 h10 = __builtin_bit_cast(bfx8, *reinterpret_cast<const uint4*>(&hb[16 + l15][col0]));
      bfx8 bw1 = __builtin_bit_cast(bfx8, *reinterpret_cast<const uint4*>(&lw[wv * 16 + l15][col1]));
      bfx8 h01 = __builtin_bit_cast(bfx8, *reinterpret_cast<const uint4*>(&hb[l15][col1]));
      bfx8 h11 = __builtin_bit_cast(bfx8, *reinterpret_cast<const uint4*>(&hb[16 + l15][col1]));
      a0a = __builtin_amdgcn_mfma_f32_16x16x32_bf16(h00, bw0, a0a, 0, 0, 0);
      a1a = __builtin_amdgcn_mfma_f32_16x16x32_bf16(h10, bw0, a1a, 0, 0, 0);
      a0b = __builtin_amdgcn_mfma_f32_16x16x32_bf16(h01, bw1, a0b, 0, 0, 0);
      a1b = __builtin_amdgcn_mfma_f32_16x16x32_bf16(h11, bw1, a1b, 0, 0, 0);
    }
#pragma unroll
    for (int qq = 0; qq < 4; ++qq){
      int bb0 = (4 * l4 + qq) ^ (4 * (l15 & 7));
      int bb1 = (16 + 4 * l4 + qq) ^ (4 * (l15 & 7));
      gl2[wv][l15][bb0] = a0a[qq] + a0b[qq];
      gl2[wv][l15][bb1] = a1a[qq] + a1b[qq];
    }
    __syncthreads();

    // ---- gates + cell update (2 adjacent hidden dims per thread) ----
    int x0 = b0 ^ (4 * (jl0 & 7));
    int x1 = b0 ^ (4 * (jl1 & 7));
    float gi0 = gl2[0][jl0][x0] + blo(pc.x), gi1 = gl2[0][jl1][x1] + bhi(pc.x);
    float gf0 = gl2[1][jl0][x0] + blo(pc.y), gf1 = gl2[1][jl1][x1] + bhi(pc.y);
    float gg0 = gl2[2][jl0][x0] + blo(pc.z), gg1 = gl2[2][jl1][x1] + bhi(pc.z);
    float go0 = gl2[3][jl0][x0] + blo(pc.w), go1 = gl2[3][jl1][x1] + bhi(pc.w);
    c0 = sigm(gf0) * c0 + sigm(gi0) * tanh_f(gg0);
    float h0 = sigm(go0) * tanh_f(c0);
    c1 = sigm(gf1) * c1 + sigm(gi1) * tanh_f(gg1);
    float h1 = sigm(go1) * tanh_f(c1);

    unsigned hv = (unsigned)f2b(h0) | ((unsigned)f2b(h1) << 16);
    own_word = ((u64)(unsigned)(s + 1) << 32) | (u64)hv;
    // fire-and-forget publish: {tag s+1, h pair}
    ast64(&H64[((long)(pw * 2 + d) * 192 + sl * 8 + q) * 32 + b0], own_word);
    // layer output (plain u32 store)
    *reinterpret_cast<unsigned*>(&Y[((long)tt * 32 + b0) * 768 + d * 384 + js + jl0]) = hv;
    pc = pn; pn = p2;
  }
}

// ---------- K4: emissions  em[b][t][c] = Y2 @ fc_w^T + fc_b (u32-pair loads) ----------
__global__ __launch_bounds__(256) void fc_em(
    const u16* __restrict__ Y2, const float* __restrict__ fw,
    const float* __restrict__ fb, float* __restrict__ em)
{
  int row = blockIdx.x * 4 + (threadIdx.x >> 6);   // row = t*32+b
  int lane = threadIdx.x & 63;
  float acc[14];
#pragma unroll
  for (int c = 0; c < 14; ++c) acc[c] = 0.f;
#pragma unroll
  for (int u = 0; u < 6; ++u){
    int k2 = (lane + 64 * u) * 2;    // even index; covers 768 elems
    unsigned yv = *reinterpret_cast<const unsigned*>(&Y2[(long)row * 768 + k2]);
    float y0 = blo(yv), y1 = bhi(yv);
#pragma unroll
    for (int c = 0; c < 14; ++c){
      float2 f = *reinterpret_cast<const float2*>(&fw[c * 768 + k2]);
      acc[c] += y0 * f.x + y1 * f.y;
    }
  }
#pragma unroll
  for (int c = 0; c < 14; ++c){
    float a = acc[c];
#pragma unroll
    for (int o = 32; o > 0; o >>= 1) a += __shfl_xor(a, o);
    acc[c] = a;
  }
  if (lane == 0){
    int tt = row >> 5, b = row & 31;
#pragma unroll
    for (int c = 0; c < 14; ++c) em[(long)(b * 256 + tt) * 14 + c] = acc[c] + fb[c];
  }
}

// ---------- K5: CRF per-sequence loss (one wave per b) ----------
__global__ __launch_bounds__(64) void crf_fwd(
    const float* __restrict__ em,   // [32][256][14]
    const int* __restrict__ labels, // [32][256]
    const float* __restrict__ cs, const float* __restrict__ ce,
    const float* __restrict__ ct,   // [14][14]
    float* __restrict__ lossb)
{
  int b = blockIdx.x;
  int lane = threadIdx.x;
  const float* E = em + (long)b * 256 * 14;
  const int* L = labels + b * 256;

  float sc = 0.f;
  for (int t = lane; t < 256; t += 64){
    int lt = L[t];
    sc += E[t * 14 + lt];
    if (t < 255) sc += ct[lt * 14 + L[t + 1]];
  }
#pragma unroll
  for (int o = 32; o > 0; o >>= 1) sc += __shfl_xor(sc, o);
  float score = sc + cs[L[0]] + ce[L[255]];

  __shared__ float al[2][16];
  int j = lane >> 2, ih = lane & 3;
  if (lane < 16){
    al[0][lane] = (lane < 14) ? (cs[lane] + E[lane]) : -1e30f;
    al[1][lane] = -1e30f;
  }
  __syncthreads();
  float tr[4];
#pragma unroll
  for (int w = 0; w < 4; ++w){
    int i = ih * 4 + w;
    tr[w] = (i < 14 && j < 14) ? ct[i * 14 + j] : -1e30f;
  }
  for (int t = 1; t < 256; ++t){
    int par = t & 1;
    float vals[4]; float m = -1e30f;
#pragma unroll
    for (int w = 0; w < 4; ++w){
      int i = ih * 4 + w;
      float v = al[par ^ 1][i] + tr[w];
      vals[w] = v; m = fmaxf(m, v);
    }
    m = fmaxf(m, __shfl_xor(m, 1));
    m = fmaxf(m, __shfl_xor(m, 2));
    float s = 0.f;
#pragma unroll
    for (int w = 0; w < 4; ++w) s += __expf(vals[w] - m);
    s += __shfl_xor(s, 1);
    s += __shfl_xor(s, 2);
    if (ih == 0 && j < 14) al[par][j] = m + __logf(s) + E[t * 14 + j];
    __syncthreads();
  }
  float v = (lane < 14) ? (al[1][lane] + ce[lane]) : -1e30f;
  float mm = v;
#pragma unroll
  for (int o = 32; o > 0; o >>= 1) mm = fmaxf(mm, __shfl_xor(mm, o));
  float ss = (lane < 14) ? __expf(v - mm) : 0.f;
#pragma unroll
  for (int o = 32; o > 0; o >>= 1) ss += __shfl_xor(ss, o);
  if (lane == 0) lossb[b] = (mm + __logf(ss)) - score;
}

// ---------- K6: final sum ----------
__global__ __launch_bounds__(64) void final_sum(const float* __restrict__ lb, float* __restrict__ out){
  int lane = threadIdx.x;
  float v = (lane < 32) ? lb[lane] : 0.f;
#pragma unroll
  for (int o = 32; o > 0; o >>= 1) v += __shfl_xor(v, o);
  if (lane == 0) out[0] = v;
}

// ---------- host ----------
extern "C" void kernel_launch(void* const* d_in, const int* in_sizes, int n_in,
                              void* d_out, int out_size, void* d_ws, size_t ws_size,
                              hipStream_t stream)
{
  const int*   ids = (const int*)d_in[0];
  const int*   lab = (const int*)d_in[1];
  const float* we  = (const float*)d_in[2];
  const float* pe  = (const float*)d_in[3];
  const float* te  = (const float*)d_in[4];
  const float* lng = (const float*)d_in[5];
  const float* lnb = (const float*)d_in[6];
  const float* wih = (const float*)d_in[7];
  const float* whh = (const float*)d_in[8];
  const float* bih = (const float*)d_in[9];
  const float* bhh = (const float*)d_in[10];
  const float* fcw = (const float*)d_in[11];
  const float* fcb = (const float*)d_in[12];
  const float* cs  = (const float*)d_in[13];
  const float* ce  = (const float*)d_in[14];
  const float* ct  = (const float*)d_in[15];
  float* out = (float*)d_out;

  char* ws = (char*)d_ws;
  size_t off = 0;
  u16* X0  = (u16*)(ws + off); off += (size_t)8192 * 768 * 2;          // 12.58 MB
  u16* Y1  = (u16*)(ws + off); off += (size_t)8192 * 768 * 2;          // 12.58 MB
  u16* PRE = (u16*)(ws + off); off += (size_t)2 * 256 * 32 * 1536 * 2; // 50.33 MB
  float* EM = (float*)(ws + off); off += (size_t)32 * 256 * 14 * 4;    // 0.46 MB
  u64* H64a = (u64*)(ws + off); off += (size_t)2 * 2 * 192 * 32 * 8;   // 196 KB
  u64* H64b = (u64*)(ws + off); off += (size_t)2 * 2 * 192 * 32 * 8;   // 196 KB
  u16* WIHB = (u16*)(ws + off); off += (size_t)2 * 2 * 1536 * 768 * 2; // 9.44 MB (both layers)
  float* LB = (float*)(ws + off); off += 128;
  u16* Y2 = X0;   // X0 dead after layer-1 pre-projection

  // convert both layers' W_ih up front (independent of everything else)
  conv_wih<<<4608, 256, 0, stream>>>(wih, WIHB);
  embed_ln<<<8192, 256, 0, stream>>>(ids, we, pe, te, lng, lnb, X0);

  // layer 0
  gemm_pre<<<dim3(128, 48), 256, 0, stream>>>(X0, WIHB, bih, bhh, PRE);
  lstm_layer<<<48, 256, 0, stream>>>(whh, PRE, Y1, H64a);
  // layer 1
  gemm_pre<<<dim3(128, 48), 256, 0, stream>>>(Y1, WIHB + (size_t)2 * 1536 * 768,
                                              bih + 2 * 1536, bhh + 2 * 1536, PRE);
  lstm_layer<<<48, 256, 0, stream>>>(whh + (size_t)2 * 1536 * 384, PRE, Y2, H64b);

  fc_em<<<2048, 256, 0, stream>>>(Y2, fcw, fcb, EM);
  crf_fwd<<<32, 64, 0, stream>>>(EM, lab, cs, ce, ct, LB);
  final_sum<<<1, 64, 0, stream>>>(LB, out);
}

// Round 12
// 2316.142 us; speedup vs baseline: 2.8162x; 1.0313x over previous
//
#include <hip/hip_runtime.h>

typedef unsigned short u16;
typedef unsigned long long u64;
typedef __bf16 bfx8 __attribute__((ext_vector_type(8)));
typedef float  fx4  __attribute__((ext_vector_type(4)));

// ---------- helpers ----------
static __device__ __forceinline__ float b2f(u16 u){
  unsigned v = ((unsigned)u) << 16;
  return __builtin_bit_cast(float, v);
}
static __device__ __forceinline__ u16 f2b(float f){
  unsigned u = __builtin_bit_cast(unsigned, f);
  u = (u + 0x7FFFu + ((u >> 16) & 1u)) >> 16;
  return (u16)u;
}
static __device__ __forceinline__ float blo(unsigned v){ return b2f((u16)(v & 0xFFFFu)); }
static __device__ __forceinline__ float bhi(unsigned v){ return b2f((u16)(v >> 16)); }
static __device__ __forceinline__ float sigm(float x){
  float cx = fminf(fmaxf(x, -30.f), 30.f);
  float e = __expf(-cx);
  return __builtin_amdgcn_rcpf(1.f + e);
}
static __device__ __forceinline__ float tanh_f(float x){
  float cx = fminf(fmaxf(x, -15.f), 15.f);
  float e = __expf(2.f * cx);
  return (e - 1.f) * __builtin_amdgcn_rcpf(e + 1.f);
}
// relaxed agent-scope 8B atomics (coherent at L3, no fences)
static __device__ __forceinline__ u64 ald64(const u64* p){
  return __hip_atomic_load(p, __ATOMIC_RELAXED, __HIP_MEMORY_SCOPE_AGENT);
}
static __device__ __forceinline__ void ast64(u64* p, u64 v){
  __hip_atomic_store(p, v, __ATOMIC_RELAXED, __HIP_MEMORY_SCOPE_AGENT);
}
// async global->LDS, 16B per lane; LDS dest = wave-uniform base + lane*16
static __device__ __forceinline__ void gload_lds16(const void* g, void* l){
  __builtin_amdgcn_global_load_lds(
      (const __attribute__((address_space(1))) void*)(g),
      (__attribute__((address_space(3))) void*)(l), 16, 0, 0);
}

// ---------- K1: embeddings + LayerNorm -> X (bf16, [T*32+b][768]) ----------
__global__ __launch_bounds__(256) void embed_ln(
    const int* __restrict__ ids, const float* __restrict__ we,
    const float* __restrict__ pe, const float* __restrict__ te,
    const float* __restrict__ lng, const float* __restrict__ lnb,
    u16* __restrict__ X)
{
  int row = blockIdx.x;            // row = t*32 + b
  int t = row >> 5, b = row & 31;
  int id = ids[b * 256 + t];
  int tid = threadIdx.x;
  int wv = tid >> 6, lane = tid & 63;
  __shared__ float red[8];
  float v[3]; float s = 0.f, s2 = 0.f;
  const float* wrow = we + (long)id * 768;
  const float* prow = pe + (long)t * 768;
#pragma unroll
  for (int u = 0; u < 3; ++u){
    int k = tid + 256 * u;
    float x = wrow[k] + prow[k] + te[k];
    v[u] = x; s += x; s2 += x * x;
  }
#pragma unroll
  for (int o = 32; o > 0; o >>= 1){ s += __shfl_xor(s, o); s2 += __shfl_xor(s2, o); }
  if (lane == 0){ red[wv] = s; red[4 + wv] = s2; }
  __syncthreads();
  float S  = red[0] + red[1] + red[2] + red[3];
  float S2 = red[4] + red[5] + red[6] + red[7];
  float mu = S * (1.f / 768.f);
  float var = S2 * (1.f / 768.f) - mu * mu;
  float rs = rsqrtf(var + 1e-12f);
#pragma unroll
  for (int u = 0; u < 3; ++u){
    int k = tid + 256 * u;
    float y = (v[u] - mu) * rs * lng[k] + lnb[k];
    X[(long)row * 768 + k] = f2b(y);
  }
}

// ---------- convert BOTH layers' W_ih (f32 -> bf16), 4 elems/thread ----------
__global__ __launch_bounds__(256) void conv_wih(
    const float* __restrict__ w, u16* __restrict__ o)
{
  long i = ((long)blockIdx.x * 256 + threadIdx.x) * 4;   // 2*2*1536*768 total
  float4 v = *reinterpret_cast<const float4*>(&w[i]);
  short4 pk;
  pk.x = (short)f2b(v.x); pk.y = (short)f2b(v.y);
  pk.z = (short)f2b(v.z); pk.w = (short)f2b(v.w);
  *reinterpret_cast<short4*>(&o[i]) = pk;
}

// ---------- K2: pre-projection GEMM, m97-style 128x128 tile, BK=32 ----------
// PRE[d][t][b][1536] = (A @ Wih^T + bias). A,W bf16 row-major [rows][768].
// 4 waves, each owns a 64x64 quadrant (4x4 fragments of 16x16x32).
// Staging via global_load_lds width=16: linear LDS, per-lane global address.
__global__ __launch_bounds__(256) void gemm_pre(
    const u16* __restrict__ A,      // [8192][768] bf16, row = t*32+b
    const u16* __restrict__ W,      // [3072][768] bf16 (pre-converted, both dirs)
    const float* __restrict__ bi,
    const float* __restrict__ bh,
    u16* __restrict__ pre)          // [2][256][32][1536] bf16
{
  __shared__ u16 la[128 * 32];      // linear [row][32] per K-step
  __shared__ u16 lb[128 * 32];
  int m0 = blockIdx.x * 128, n0 = blockIdx.y * 128;
  int tid = threadIdx.x;
  int wv = tid >> 6, lane = tid & 63;
  int l15 = lane & 15, l4 = lane >> 4;
  int wr = (wv >> 1) * 64, wc = (wv & 1) * 64;   // wave quadrant
  int srow = lane >> 2;            // staging row within 16-row block
  int scol = 8 * (lane & 3);       // staging col (8 bf16 = 16 B)

  fx4 acc[4][4];
#pragma unroll
  for (int mi = 0; mi < 4; ++mi)
#pragma unroll
    for (int ni = 0; ni < 4; ++ni){
      acc[mi][ni][0]=0.f; acc[mi][ni][1]=0.f; acc[mi][ni][2]=0.f; acc[mi][ni][3]=0.f;
    }

  for (int k0 = 0; k0 < 768; k0 += 32){
    __syncthreads();
#pragma unroll
    for (int r = 0; r < 2; ++r){
      int blk = r * 4 + wv;        // 0..7 -> rows blk*16..+15
      gload_lds16(A + (long)(m0 + blk * 16 + srow) * 768 + k0 + scol,
                  &la[blk * 512]);
      gload_lds16(W + (long)(n0 + blk * 16 + srow) * 768 + k0 + scol,
                  &lb[blk * 512]);
    }
    __syncthreads();               // compiler inserts vmcnt(0) before barrier

    bfx8 af[4], bf[4];
#pragma unroll
    for (int mi = 0; mi < 4; ++mi)
      af[mi] = __builtin_bit_cast(bfx8,
        *reinterpret_cast<const uint4*>(&la[(wr + mi * 16 + l15) * 32 + 8 * l4]));
#pragma unroll
    for (int ni = 0; ni < 4; ++ni)
      bf[ni] = __builtin_bit_cast(bfx8,
        *reinterpret_cast<const uint4*>(&lb[(wc + ni * 16 + l15) * 32 + 8 * l4]));
#pragma unroll
    for (int mi = 0; mi < 4; ++mi)
#pragma unroll
      for (int ni = 0; ni < 4; ++ni)
        acc[mi][ni] = __builtin_amdgcn_mfma_f32_16x16x32_bf16(af[mi], bf[ni], acc[mi][ni], 0, 0, 0);
  }

#pragma unroll
  for (int ni = 0; ni < 4; ++ni){
    int n = n0 + wc + ni * 16 + l15;
    int d = (n >= 1536) ? 1 : 0;
    int np = n - d * 1536;
    float bias = bi[n] + bh[n];
#pragma unroll
    for (int mi = 0; mi < 4; ++mi){
#pragma unroll
      for (int q = 0; q < 4; ++q){
        int m = m0 + wr + mi * 16 + 4 * l4 + q;
        int tt = m >> 5, bb = m & 31;
        float vv = acc[mi][ni][q] + bias;
        pre[((long)((d * 256 + tt) * 32 + bb)) * 1536 + np] = f2b(vv);
      }
    }
  }
}

// ---------- K3: one bidirectional LSTM layer (48 WGs, dataflow-synced) ----------
// EXACT R6 structure (measured 1052-1088 us): commit-every-pass tag-poll,
// register self-skip via unrolled static-index conditional moves.
// H64: [2 parity][2 dir][192 dimpair][32 b]; u64 = {tag:high32, h pair:low32}
__global__ __launch_bounds__(256) void lstm_layer(
    const float* __restrict__ Whh,  // [2][1536][384] f32 this layer
    const u16*  __restrict__ pre,   // [2][256][32][1536] bf16
    u16* __restrict__ Y,            // [256][32][768] bf16
    u64* __restrict__ H64)
{
  __shared__ u16 lw[64][386];        // W slice bf16, XOR-swizzled cols
  __shared__ u16 hb[32][386];        // staged h, XOR-swizzled cols
  __shared__ float gl2[4][16][33];   // [gate][jl][b^swz]
  int wg = blockIdx.x;
  int d = wg / 24, sl = wg - d * 24;
  int js = sl * 16;
  int tid = threadIdx.x;
  int wv = tid >> 6, lane = tid & 63;
  int l15 = lane & 15, l4 = lane >> 4;
  int b0 = tid & 31, q = tid >> 5;   // q 0..7
  int jl0 = 2 * q, jl1 = 2 * q + 1;

  // 1) publish own h_{-1} slice first: parity 1, tag 0, h = 0
  ast64(&H64[((long)(1 * 2 + d) * 192 + sl * 8 + q) * 32 + b0], 0ull);
  u64 own_word = 0ull;               // last word this thread published

  // 2) stage Whh slice -> lw (f32 -> bf16, swizzled), float4 loads
  for (int i = tid; i < 64 * 96; i += 256){
    int rr = i / 96, c4 = i - rr * 96;
    const float* src = Whh + ((long)(d * 1536 + (rr >> 4) * 384 + js + (rr & 15))) * 384 + 4 * c4;
    float4 v = *reinterpret_cast<const float4*>(src);
    short4 pk;
    pk.x = (short)f2b(v.x); pk.y = (short)f2b(v.y);
    pk.z = (short)f2b(v.z); pk.w = (short)f2b(v.w);
    *reinterpret_cast<short4*>(&lw[rr][(4 * c4) ^ (8 * (rr & 7))]) = pk;
  }
  __syncthreads();

  float c0 = 0.f, c1 = 0.f;

  // prefetch pre for s=0 and s=1 (distance-2 pipeline)
  int t0 = d ? 255 : 0;
  int t1 = d ? 254 : 1;
  const u16* pb0 = pre + ((long)(d * 256 + t0) * 32 + b0) * 1536 + js + jl0;
  const u16* pb1 = pre + ((long)(d * 256 + t1) * 32 + b0) * 1536 + js + jl0;
  uint4 pc, pn;
  pc.x = *reinterpret_cast<const unsigned*>(pb0 + 0 * 384);
  pc.y = *reinterpret_cast<const unsigned*>(pb0 + 1 * 384);
  pc.z = *reinterpret_cast<const unsigned*>(pb0 + 2 * 384);
  pc.w = *reinterpret_cast<const unsigned*>(pb0 + 3 * 384);
  pn.x = *reinterpret_cast<const unsigned*>(pb1 + 0 * 384);
  pn.y = *reinterpret_cast<const unsigned*>(pb1 + 1 * 384);
  pn.z = *reinterpret_cast<const unsigned*>(pb1 + 2 * 384);
  pn.w = *reinterpret_cast<const unsigned*>(pb1 + 3 * 384);

  for (int s = 0; s < 256; ++s){
    int tt = d ? (255 - s) : s;
    int pr = (s + 1) & 1;            // read parity (holds h_{s-1}, tag s)
    int pw = s & 1;                  // write parity (h_s, tag s+1)

    // ---- stage h_{s-1}: batch-parallel poll, commit every pass (R6) ----
    {
      const u64* hsrc = H64 + (long)(pr * 2 + d) * 192 * 32;
      unsigned tagv = (unsigned)s;
      __builtin_amdgcn_s_sleep(2);   // settle: let publishes land in L3
      for (;;){
        u64 vb[24];
#pragma unroll
        for (int i = 0; i < 24; ++i) vb[i] = ald64(&hsrc[tid + 256 * i]);
#pragma unroll
        for (int i = 0; i < 24; ++i) if (i == sl) vb[i] = own_word;  // static idx
        bool ok = true;
#pragma unroll
        for (int i = 0; i < 24; ++i) ok = ok && ((unsigned)(vb[i] >> 32) == tagv);
#pragma unroll
        for (int i = 0; i < 24; ++i){
          int f = tid + 256 * i;
          int bb = f & 31, j2 = f >> 5;
          *reinterpret_cast<unsigned*>(&hb[bb][(2 * j2) ^ (8 * (bb & 7))]) = (unsigned)vb[i];
        }
        if (__syncthreads_and((int)ok)) break;
      }
    }

    // issue pre prefetch for s+2 AFTER poll (never inside a poll vmcnt window)
    int s2 = (s + 2 < 256) ? (s + 2) : 255;
    int t2 = d ? (255 - s2) : s2;
    const u16* pb2 = pre + ((long)(d * 256 + t2) * 32 + b0) * 1536 + js + jl0;
    uint4 p2;
    p2.x = *reinterpret_cast<const unsigned*>(pb2 + 0 * 384);
    p2.y = *reinterpret_cast<const unsigned*>(pb2 + 1 * 384);
    p2.z = *reinterpret_cast<const unsigned*>(pb2 + 2 * 384);
    p2.w = *reinterpret_cast<const unsigned*>(pb2 + 3 * 384);

    // ---- MFMA: gates(g=wv, b, jl=l15) over K=384, two interleaved chains ----
    fx4 a0a, a0b, a1a, a1b;
#pragma unroll
    for (int z = 0; z < 4; ++z){ a0a[z]=0.f; a0b[z]=0.f; a1a[z]=0.f; a1b[z]=0.f; }
#pragma unroll
    for (int kk = 0; kk < 12; kk += 2){
      int col0 = (kk * 32 + 8 * l4) ^ (8 * (l15 & 7));
      int col1 = ((kk + 1) * 32 + 8 * l4) ^ (8 * (l15 & 7));
      bfx8 bw0 = __builtin_bit_cast(bfx8, *reinterpret_cast<const uint4*>(&lw[wv * 16 + l15][col0]));
      bfx8 h00 = __builtin_bit_cast(bfx8, *reinterpret_cast<const uint4*>(&hb[l15][col0]));
      bfx8 h10 = __builtin_bit_cast(bfx8, *reinterpret_cast<const uint4*>(&hb[16 + l15][col0]));
      bfx8 bw1 = __builtin_bit_cast(bfx8, *reinterpret_cast<const uint4*>(&lw[wv * 16 + l15][col1]));
      bfx8 h01 = __builtin_bit_cast(bfx8, *reinterpret_cast<const uint4*>(&hb[l15][col1]));
      bfx8 h11 = __builtin_bit_cast(bfx8, *reinterpret_cast<const uint4*>(&hb[16 + l15][col1]));
      a0a = __builtin_amdgcn_mfma_f32_16x16x32_bf16(h00, bw0, a0a, 0, 0, 0);
      a1a = __builtin_amdgcn_mfma_f32_16x16x32_bf16(h10, bw0, a1a, 0, 0, 0);
      a0b = __builtin_amdgcn_mfma_f32_16x16x32_bf16(h01, bw1, a0b, 0, 0, 0);
      a1b = __builtin_amdgcn_mfma_f32_16x16x32_bf16(h11, bw1, a1b, 0, 0, 0);
    }
#pragma unroll
    for (int qq = 0; qq < 4; ++qq){
      int bb0 = (4 * l4 + qq) ^ (4 * (l15 & 7));
      int bb1 = (16 + 4 * l4 + qq) ^ (4 * (l15 & 7));
      gl2[wv][l15][bb0] = a0a[qq] + a0b[qq];
      gl2[wv][l15][bb1] = a1a[qq] + a1b[qq];
    }
    __syncthreads();

    // ---- gates + cell update (2 adjacent hidden dims per thread) ----
    int x0 = b0 ^ (4 * (jl0 & 7));
    int x1 = b0 ^ (4 * (jl1 & 7));
    float gi0 = gl2[0][jl0][x0] + blo(pc.x), gi1 = gl2[0][jl1][x1] + bhi(pc.x);
    float gf0 = gl2[1][jl0][x0] + blo(pc.y), gf1 = gl2[1][jl1][x1] + bhi(pc.y);
    float gg0 = gl2[2][jl0][x0] + blo(pc.z), gg1 = gl2[2][jl1][x1] + bhi(pc.z);
    float go0 = gl2[3][jl0][x0] + blo(pc.w), go1 = gl2[3][jl1][x1] + bhi(pc.w);
    c0 = sigm(gf0) * c0 + sigm(gi0) * tanh_f(gg0);
    float h0 = sigm(go0) * tanh_f(c0);
    c1 = sigm(gf1) * c1 + sigm(gi1) * tanh_f(gg1);
    float h1 = sigm(go1) * tanh_f(c1);

    unsigned hv = (unsigned)f2b(h0) | ((unsigned)f2b(h1) << 16);
    own_word = ((u64)(unsigned)(s + 1) << 32) | (u64)hv;
    // fire-and-forget publish: {tag s+1, h pair}
    ast64(&H64[((long)(pw * 2 + d) * 192 + sl * 8 + q) * 32 + b0], own_word);
    // layer output (plain u32 store)
    *reinterpret_cast<unsigned*>(&Y[((long)tt * 32 + b0) * 768 + d * 384 + js + jl0]) = hv;
    pc = pn; pn = p2;
  }
}

// ---------- K4: emissions  em[b][t][c] = Y2 @ fc_w^T + fc_b (u32-pair loads) ----------
__global__ __launch_bounds__(256) void fc_em(
    const u16* __restrict__ Y2, const float* __restrict__ fw,
    const float* __restrict__ fb, float* __restrict__ em)
{
  int row = blockIdx.x * 4 + (threadIdx.x >> 6);   // row = t*32+b
  int lane = threadIdx.x & 63;
  float acc[14];
#pragma unroll
  for (int c = 0; c < 14; ++c) acc[c] = 0.f;
#pragma unroll
  for (int u = 0; u < 6; ++u){
    int k2 = (lane + 64 * u) * 2;    // even index; covers 768 elems
    unsigned yv = *reinterpret_cast<const unsigned*>(&Y2[(long)row * 768 + k2]);
    float y0 = blo(yv), y1 = bhi(yv);
#pragma unroll
    for (int c = 0; c < 14; ++c){
      float2 f = *reinterpret_cast<const float2*>(&fw[c * 768 + k2]);
      acc[c] += y0 * f.x + y1 * f.y;
    }
  }
#pragma unroll
  for (int c = 0; c < 14; ++c){
    float a = acc[c];
#pragma unroll
    for (int o = 32; o > 0; o >>= 1) a += __shfl_xor(a, o);
    acc[c] = a;
  }
  if (lane == 0){
    int tt = row >> 5, b = row & 31;
#pragma unroll
    for (int c = 0; c < 14; ++c) em[(long)(b * 256 + tt) * 14 + c] = acc[c] + fb[c];
  }
}

// ---------- K5: CRF per-sequence loss (one wave per b) ----------
__global__ __launch_bounds__(64) void crf_fwd(
    const float* __restrict__ em,   // [32][256][14]
    const int* __restrict__ labels, // [32][256]
    const float* __restrict__ cs, const float* __restrict__ ce,
    const float* __restrict__ ct,   // [14][14]
    float* __restrict__ lossb)
{
  int b = blockIdx.x;
  int lane = threadIdx.x;
  const float* E = em + (long)b * 256 * 14;
  const int* L = labels + b * 256;

  float sc = 0.f;
  for (int t = lane; t < 256; t += 64){
    int lt = L[t];
    sc += E[t * 14 + lt];
    if (t < 255) sc += ct[lt * 14 + L[t + 1]];
  }
#pragma unroll
  for (int o = 32; o > 0; o >>= 1) sc += __shfl_xor(sc, o);
  float score = sc + cs[L[0]] + ce[L[255]];

  __shared__ float al[2][16];
  int j = lane >> 2, ih = lane & 3;
  if (lane < 16){
    al[0][lane] = (lane < 14) ? (cs[lane] + E[lane]) : -1e30f;
    al[1][lane] = -1e30f;
  }
  __syncthreads();
  float tr[4];
#pragma unroll
  for (int w = 0; w < 4; ++w){
    int i = ih * 4 + w;
    tr[w] = (i < 14 && j < 14) ? ct[i * 14 + j] : -1e30f;
  }
  for (int t = 1; t < 256; ++t){
    int par = t & 1;
    float vals[4]; float m = -1e30f;
#pragma unroll
    for (int w = 0; w < 4; ++w){
      int i = ih * 4 + w;
      float v = al[par ^ 1][i] + tr[w];
      vals[w] = v; m = fmaxf(m, v);
    }
    m = fmaxf(m, __shfl_xor(m, 1));
    m = fmaxf(m, __shfl_xor(m, 2));
    float s = 0.f;
#pragma unroll
    for (int w = 0; w < 4; ++w) s += __expf(vals[w] - m);
    s += __shfl_xor(s, 1);
    s += __shfl_xor(s, 2);
    if (ih == 0 && j < 14) al[par][j] = m + __logf(s) + E[t * 14 + j];
    __syncthreads();
  }
  float v = (lane < 14) ? (al[1][lane] + ce[lane]) : -1e30f;
  float mm = v;
#pragma unroll
  for (int o = 32; o > 0; o >>= 1) mm = fmaxf(mm, __shfl_xor(mm, o));
  float ss = (lane < 14) ? __expf(v - mm) : 0.f;
#pragma unroll
  for (int o = 32; o > 0; o >>= 1) ss += __shfl_xor(ss, o);
  if (lane == 0) lossb[b] = (mm + __logf(ss)) - score;
}

// ---------- K6: final sum ----------
__global__ __launch_bounds__(64) void final_sum(const float* __restrict__ lb, float* __restrict__ out){
  int lane = threadIdx.x;
  float v = (lane < 32) ? lb[lane] : 0.f;
#pragma unroll
  for (int o = 32; o > 0; o >>= 1) v += __shfl_xor(v, o);
  if (lane == 0) out[0] = v;
}

// ---------- host ----------
extern "C" void kernel_launch(void* const* d_in, const int* in_sizes, int n_in,
                              void* d_out, int out_size, void* d_ws, size_t ws_size,
                              hipStream_t stream)
{
  const int*   ids = (const int*)d_in[0];
  const int*   lab = (const int*)d_in[1];
  const float* we  = (const float*)d_in[2];
  const float* pe  = (const float*)d_in[3];
  const float* te  = (const float*)d_in[4];
  const float* lng = (const float*)d_in[5];
  const float* lnb = (const float*)d_in[6];
  const float* wih = (const float*)d_in[7];
  const float* whh = (const float*)d_in[8];
  const float* bih = (const float*)d_in[9];
  const float* bhh = (const float*)d_in[10];
  const float* fcw = (const float*)d_in[11];
  const float* fcb = (const float*)d_in[12];
  const float* cs  = (const float*)d_in[13];
  const float* ce  = (const float*)d_in[14];
  const float* ct  = (const float*)d_in[15];
  float* out = (float*)d_out;

  char* ws = (char*)d_ws;
  size_t off = 0;
  u16* X0  = (u16*)(ws + off); off += (size_t)8192 * 768 * 2;          // 12.58 MB
  u16* Y1  = (u16*)(ws + off); off += (size_t)8192 * 768 * 2;          // 12.58 MB
  u16* PRE = (u16*)(ws + off); off += (size_t)2 * 256 * 32 * 1536 * 2; // 50.33 MB
  float* EM = (float*)(ws + off); off += (size_t)32 * 256 * 14 * 4;    // 0.46 MB
  u64* H64a = (u64*)(ws + off); off += (size_t)2 * 2 * 192 * 32 * 8;   // 196 KB
  u64* H64b = (u64*)(ws + off); off += (size_t)2 * 2 * 192 * 32 * 8;   // 196 KB
  u16* WIHB = (u16*)(ws + off); off += (size_t)2 * 2 * 1536 * 768 * 2; // 9.44 MB (both layers)
  float* LB = (float*)(ws + off); off += 128;
  u16* Y2 = X0;   // X0 dead after layer-1 pre-projection

  // convert both layers' W_ih up front (independent of everything else)
  conv_wih<<<4608, 256, 0, stream>>>(wih, WIHB);
  embed_ln<<<8192, 256, 0, stream>>>(ids, we, pe, te, lng, lnb, X0);

  // layer 0
  gemm_pre<<<dim3(64, 24), 256, 0, stream>>>(X0, WIHB, bih, bhh, PRE);
  lstm_layer<<<48, 256, 0, stream>>>(whh, PRE, Y1, H64a);
  // layer 1
  gemm_pre<<<dim3(64, 24), 256, 0, stream>>>(Y1, WIHB + (size_t)2 * 1536 * 768,
                                             bih + 2 * 1536, bhh + 2 * 1536, PRE);
  lstm_layer<<<48, 256, 0, stream>>>(whh + (size_t)2 * 1536 * 384, PRE, Y2, H64b);

  fc_em<<<2048, 256, 0, stream>>>(Y2, fcw, fcb, EM);
  crf_fwd<<<32, 64, 0, stream>>>(EM, lab, cs, ce, ct, LB);
  final_sum<<<1, 64, 0, stream>>>(LB, out);
}